// Round 1
// baseline (45.444 us; speedup 1.0000x reference)
//
#include <hip/hip_runtime.h>

#define HH 512
#define WW 512
#define CC 3
#define BANDS 8
#define ROWS_PER_BAND 64  // HH / BANDS

// d_ws layout: float blocks[B][4][4]  (B=32 -> 512 floats)

__global__ void zero_blocks_kernel(float* __restrict__ blocks, int n) {
    int i = blockIdx.x * blockDim.x + threadIdx.x;
    if (i < n) blocks[i] = 0.0f;
}

__global__ __launch_bounds__(256) void lap_block_sum_kernel(
    const float* __restrict__ gt, const float* __restrict__ sp,
    float* __restrict__ blocks)
{
    __shared__ float ring[4][WW];   // 8 KiB ring of t = gt - sp rows
    __shared__ float red[4][4];     // per-wave partials

    const int band = blockIdx.x;
    const int c    = blockIdx.y;
    const int b    = blockIdx.z;
    const int t    = threadIdx.x;
    const int w0   = 2 * t;
    const int w1   = w0 + 1;

    const int h0 = band * ROWS_PER_BAND;
    const size_t plane = (size_t)(b * CC + c) * (size_t)(HH * WW);
    const float* __restrict__ gtp = gt + plane;
    const float* __restrict__ spp = sp + plane;

    // load row hr (with vertical reflect) as t = gt - sp into ring[hr&3]
    auto load_row = [&](int hr) {
        int hs = hr < 0 ? 1 : (hr > HH - 1 ? HH - 2 : hr);
        const float2 g = *(const float2*)(gtp + (size_t)hs * WW + w0);
        const float2 s = *(const float2*)(spp + (size_t)hs * WW + w0);
        float2 d = make_float2(g.x - s.x, g.y - s.y);
        *(float2*)&ring[hr & 3][w0] = d;
    };

    load_row(h0 - 1);
    load_row(h0);

    const int fr0 = c * HH + h0;       // flat row index; v constant per band
    const int v   = fr0 / 384;
    // hz per row-phase m = fr % 3 (both columns of this thread share hz)
    const int hz_m0 = (0 * 512 + w0) / 384;
    const int hz_m1 = (1 * 512 + w0) / 384;
    const int hz_m2 = (2 * 512 + w0) / 384;

    const int wm1 = (w0 == 0)      ? 1      : w0 - 1;  // column reflect left
    const int wp2 = (w1 == WW - 1) ? WW - 2 : w1 + 1;  // column reflect right

    float acc0 = 0.0f, acc1 = 0.0f, acc2 = 0.0f, acc3 = 0.0f;

    int m = fr0 % 3;
    #pragma unroll 4
    for (int h = h0; h < h0 + ROWS_PER_BAND; ++h) {
        load_row(h + 1);
        __syncthreads();
        const float* __restrict__ r0 = ring[(h - 1) & 3];
        const float* __restrict__ r1 = ring[h & 3];
        const float* __restrict__ r2 = ring[(h + 1) & 3];

        float cm  = r0[wm1] + r1[wm1] + r2[wm1];
        float c0v = r1[w0];
        float cs0 = r0[w0] + c0v + r2[w0];
        float c1v = r1[w1];
        float cs1 = r0[w1] + c1v + r2[w1];
        float cp  = r0[wp2] + r1[wp2] + r2[wp2];

        float lap0 = (cm  + cs0 + cs1 - 9.0f * c0v) * 0.0625f;
        float lap1 = (cs0 + cs1 + cp  - 9.0f * c1v) * 0.0625f;
        float s = fabsf(lap0) + fabsf(lap1);

        int hz = (m == 0) ? hz_m0 : ((m == 1) ? hz_m1 : hz_m2);
        acc0 += (hz == 0) ? s : 0.0f;
        acc1 += (hz == 1) ? s : 0.0f;
        acc2 += (hz == 2) ? s : 0.0f;
        acc3 += (hz == 3) ? s : 0.0f;

        m = (m == 2) ? 0 : m + 1;
    }

    // wave64 butterfly reduce of the 4 accumulators
    #pragma unroll
    for (int off = 32; off > 0; off >>= 1) {
        acc0 += __shfl_xor(acc0, off);
        acc1 += __shfl_xor(acc1, off);
        acc2 += __shfl_xor(acc2, off);
        acc3 += __shfl_xor(acc3, off);
    }
    const int wave = t >> 6;
    const int lane = t & 63;
    if (lane == 0) {
        red[wave][0] = acc0; red[wave][1] = acc1;
        red[wave][2] = acc2; red[wave][3] = acc3;
    }
    __syncthreads();
    if (t < 4) {
        float r = red[0][t] + red[1][t] + red[2][t] + red[3][t];
        atomicAdd(&blocks[(b * 4 + v) * 4 + t], r);
    }
}

__global__ void finalize_kernel(const float* __restrict__ blocks,
                                float* __restrict__ out, int B) {
    int t = threadIdx.x;
    float m = 0.0f;
    if (t < B) {
        m = blocks[t * 16];
        #pragma unroll
        for (int i = 1; i < 16; ++i) m = fmaxf(m, blocks[t * 16 + i]);
    }
    // sum across lanes 0..31 (B = 32)
    #pragma unroll
    for (int off = 16; off > 0; off >>= 1) m += __shfl_down(m, off, 32);
    if (t == 0) out[0] = m;
}

extern "C" void kernel_launch(void* const* d_in, const int* in_sizes, int n_in,
                              void* d_out, int out_size, void* d_ws, size_t ws_size,
                              hipStream_t stream) {
    const float* gt = (const float*)d_in[0];
    const float* sp = (const float*)d_in[1];
    float* blocks = (float*)d_ws;
    float* out = (float*)d_out;

    const int B = in_sizes[0] / (CC * HH * WW);  // 32

    zero_blocks_kernel<<<1, 512, 0, stream>>>(blocks, B * 16);

    dim3 grid(BANDS, CC, B);
    lap_block_sum_kernel<<<grid, 256, 0, stream>>>(gt, sp, blocks);

    finalize_kernel<<<1, 64, 0, stream>>>(blocks, out, B);
}